// Round 13
// baseline (361.507 us; speedup 1.0000x reference)
//
#include <hip/hip_runtime.h>
#include <stdint.h>

static constexpr int kN = 128;
static constexpr int kTri = (kN * (kN - 1)) / 2;   // 8128 (BT scratch indexing)
static constexpr int kTriD = (kN * (kN + 1)) / 2;  // 8256 cells incl. diagonal
static constexpr int kThreads = 1024;
static constexpr int kSerialK = 16;  // k <= this: one row per lane, no reduction
static constexpr float kNeg = -9999.0f;
static constexpr float kThresh = -9000.0f;
static constexpr float kArcBonus = 5.0f;
static constexpr int kDynLds = kTriD * 16;  // 132,096 B (one float4 quad per cell)

__device__ __forceinline__ int rowBase(int i) { return (i * (2 * kN - 1 - i)) / 2; }
__device__ __forceinline__ int colBaseD(int c) { return (c * (c + 1)) / 2; }  // cells (r<=c, c)
// XOR bank swizzle: permutes b128 phase within each aligned 8-quad block
// (bijective; applied to ALL chart accesses). Breaks the quadratic diq pattern.
__device__ __forceinline__ int sw(int idx) { return idx ^ ((idx >> 3) & 7); }

// LDS-only workgroup barrier: orders LDS without draining vmcnt (wsBT stores
// and vL/vR prefetch loads stay in flight across steps).
__device__ __forceinline__ void ldsBarrier() {
    asm volatile("s_waitcnt lgkmcnt(0)\n\ts_barrier" ::: "memory");
}

template <int CTRL>
__device__ __forceinline__ float dppMax(float x) {
    const int y = __builtin_amdgcn_update_dpp(__float_as_int(x), __float_as_int(x),
                                              CTRL, 0xF, 0xF, true);
    return fmaxf(x, __int_as_float(y));
}
__device__ __forceinline__ float swzMax16(float x) {  // xor-16 within 32 lanes
    const int y = __builtin_amdgcn_ds_swizzle(__float_as_int(x), 0x401F);
    return fmaxf(x, __int_as_float(y));
}

// Thread's (i, j, active, P, lp) for step k. Uniform scalar math.
__device__ __forceinline__ void mapK(int k, int tid, int& i, int& j, bool& act,
                                     int& P, int& lp) {
    const int R = kN - k;
    if (k <= kSerialK) {
        P = 1; lp = 0; i = tid; j = tid + k; act = (tid < R);
    } else {
        P = 2; lp = 1;
        while (P < 64 && ((P << 1) * R) <= kThreads) { P <<= 1; ++lp; }
        i = tid >> lp; j = i + k; act = (i < R);
    }
}

// Quad per cell: {x=s00, y=s11, z=s01, w=s10}, col-major incl. diagonal (diag=0).
// SHARED-BASE argmax: p00=(base+vL)+5 and p10=(base+vR)+5 are monotone images
// of the same base sequence, so max/argmax track `base` once (values exact:
// fp-add monotone + max attained => max p00 == image(max base)).
__device__ __forceinline__ void scanChunk(const float4* __restrict__ Q4,
                                          int i, int j, int k, int mlo, int mhi,
                                          float vL,
                                          float& bmax, int& ib,
                                          float& v01, int& i01,
                                          float& v11, int& i11) {
    const int qjb = colBaseD(j);  // + r => cell (r, j)
    int q, mstart;
    float4 cur;
    if (mlo == 0) {
        q = i + 1;
        cur = Q4[sw(qjb + q)];  // quad(i+1, j); diagonal zeros when k==1
        bmax = cur.z; ib = 0;   // base(0) = 0 + s01[i+1][j]
        const float p00 = (cur.z + vL) + kArcBonus;
        v01 = (p00 > kThresh) ? p00 : kNeg; i01 = 0;  // part00 seed
        mstart = 1;
    } else {
        q = i + mlo;
        cur = Q4[sw(qjb + q)];
        mstart = mlo;
    }
    int dA = colBaseD(q) + i;  // cell (i, q)
    int dInc = q + 1;          // colBaseD(q+1) - colBaseD(q)
#pragma unroll 4
    for (int m = mstart; m < mhi; ++m) {
        const float4 nxt = Q4[sw(qjb + q + 1)];  // quad(q+1, j); diag zeros at m==k-1
        const float4 diq = Q4[sw(dA)];           // quad(i, q)
        const float base = diq.y + nxt.z;        // s11[i][q] + s01[q+1][j]
        const float p01 = diq.z + cur.x;         // s01[i][q] + s00[q][j]
        const float p11 = diq.w + cur.y;         // s10[i][q] + s11[q][j]
        if (base > bmax) { bmax = base; ib = m; }  // strict > keeps earliest m
        if (p01 > v01) { v01 = p01; i01 = m; }
        if (p11 > v11) { v11 = p11; i11 = m; }
        cur = nxt;
        dA += dInc; ++dInc;
        ++q;
    }
}

__device__ __forceinline__ void writeCell(float4* __restrict__ Q4,
                                          uint32_t* __restrict__ wsBT,
                                          int i, int j, int k,
                                          float gb, int ib, float vLc, float vRc,
                                          float v01, int i01, float v11, int i11) {
    const float v00 = (gb + vLc) + kArcBonus;
    const float v10 = (gb + vRc) + kArcBonus;
    const float new10 = (v10 > kThresh) ? v10 : kNeg;
    if (new10 > v11) { v11 = new10; i11 = k; }  // q=j candidate; strict > keeps earlier q
    float4 w = make_float4(kNeg, kNeg, kNeg, kNeg);
    uint32_t p = 0;
    if (v00 > kThresh) { w.x = v00; p |= (uint32_t)(i + ib); }
    if (v01 > kThresh) { w.z = v01; p |= (uint32_t)(i + i01) << 8; }
    if (v10 > kThresh) { w.w = v10; p |= (uint32_t)(i + ib) << 16; }
    if (v11 > kThresh) { w.y = v11; p |= (uint32_t)(i + i11) << 24; }
    Q4[sw(colBaseD(j) + i)] = w;      // one ds_write_b128
    wsBT[rowBase(i) + k - 1] = p;     // lone global store; not drained per step
}

__global__ __launch_bounds__(kThreads) void eisner_dp(
    const float* __restrict__ vinfo,  // [B][N][N] fp32
    float* __restrict__ outS,         // [B][N][N][2][2] fp32 scores
    float* __restrict__ outBT,        // [B][N][N][2][2] fp32 backtrace (integer-valued)
    uint32_t* __restrict__ btPacked)  // [B][kTri] packed backtrace bytes (d_ws)
{
    extern __shared__ float4 Q4[];

    const int tid = threadIdx.x;
    const int b = blockIdx.x;
    const float* v = vinfo + (size_t)b * kN * kN;
    uint32_t* wsBT = btPacked + (size_t)b * kTri;

    // Diagonal quads = 0. Off-diagonal cells need no init (written before read).
    const float4 zeroq = make_float4(0.f, 0.f, 0.f, 0.f);
    if (tid < kN) Q4[sw(colBaseD(tid) + tid)] = zeroq;

    // Prefetch step-1 mapping + vL/vR.
    int ci, cj; bool cact; int cP, clp;
    mapK(1, tid, ci, cj, cact, cP, clp);
    float vL = cact ? v[cj * kN + ci] : 0.f;
    float vR = cact ? v[ci * kN + cj] : 0.f;
    __syncthreads();

    for (int k = 1; k < kN; ++k) {
        const int R = kN - k;
        const int laneId = tid & 63;

        float bmax = -3.0e38f, v01 = -3.0e38f, v11 = -3.0e38f;
        int ib = 0, i01 = 0, i11 = 0x7FFFFFFF;
        const int i = ci, j = cj;
        const bool act = cact;
        const int P = cP, lp = clp;
        const float vLc = vL, vRc = vR;  // keep: prefetch below overwrites vL/vR

        if (P == 1) {
            if (act) {
                scanChunk(Q4, i, j, k, 0, k, vLc, bmax, ib, v01, i01, v11, i11);
            }
        } else {
            int C = ((k + P - 1) >> lp) | 1;  // odd chunk
            const int l = tid & (P - 1);
            const int mlo = l * C;
            const int mhi = (mlo + C < k) ? (mlo + C) : k;
            ib = i01 = 0x7FFFFFFF;
            if (act && mlo < mhi) {
                scanChunk(Q4, i, j, k, mlo, mhi, vLc, bmax, ib, v01, i01, v11, i11);
            }
        }

        // Prefetch next step's mapping + vL/vR (overlaps reduction + barrier).
        if (k + 1 < kN) {
            mapK(k + 1, tid, ci, cj, cact, cP, clp);
            vL = cact ? v[cj * kN + ci] : 0.f;
            vR = cact ? v[ci * kN + cj] : 0.f;
        }

        if (P == 1) {
            if (act) {
                writeCell(Q4, wsBT, i, j, k, bmax, ib, vLc, vRc, v01, i01, v11, i11);
            }
        } else {
            const bool waveActive = (((tid & ~63) >> lp) < R);  // wave-uniform
            if (waveActive) {
                const int l = tid & (P - 1);
                float gB = dppMax<0x4E>(dppMax<0xB1>(bmax));
                float g01 = dppMax<0x4E>(dppMax<0xB1>(v01));
                float g11 = dppMax<0x4E>(dppMax<0xB1>(v11));
                if (P >= 8) {
                    gB = dppMax<0x141>(gB); g01 = dppMax<0x141>(g01); g11 = dppMax<0x141>(g11);
                }
                if (P >= 16) {
                    gB = dppMax<0x140>(gB); g01 = dppMax<0x140>(g01); g11 = dppMax<0x140>(g11);
                }
                if (P >= 32) {
                    gB = swzMax16(gB); g01 = swzMax16(g01); g11 = swzMax16(g11);
                }
                if (P == 64) {
                    gB = fmaxf(gB, __shfl_xor(gB, 32, 64));
                    g01 = fmaxf(g01, __shfl_xor(g01, 32, 64));
                    g11 = fmaxf(g11, __shfl_xor(g11, 32, 64));
                }
                // earliest-m via ballot (contiguous chunks => lane order == m order;
                // empty lanes hold -3e38, can never equal group max)
                const int grpStart = laneId & ~(P - 1);
                const uint64_t gmask =
                    (P == 64) ? ~0ull : (((1ull << P) - 1ull) << grpStart);
                const uint64_t mB = __ballot(bmax == gB) & gmask;
                const uint64_t m2 = __ballot(v01 == g01) & gmask;
                const uint64_t m3 = __ballot(v11 == g11) & gmask;
                const int rB = __shfl(ib, __ffsll((unsigned long long)mB) - 1, 64);
                const int r01 = __shfl(i01, __ffsll((unsigned long long)m2) - 1, 64);
                const int r11 = __shfl(i11, __ffsll((unsigned long long)m3) - 1, 64);
                if (act && l == 0) {
                    writeCell(Q4, wsBT, i, j, k, gB, rB, vLc, vRc, g01, r01, g11, r11);
                }
            }
        }
        ldsBarrier();
    }

    // Full barrier (drains vmcnt) before reading wsBT back.
    __syncthreads();

    // ---- epilogue: emit full [N][N][2][2] scores + backtrace, coalesced ----
    float4* gS4 = (float4*)(outS + (size_t)b * kN * kN * 4);
    float4* gB4 = (float4*)(outBT + (size_t)b * kN * kN * 4);
    const float4 negq = make_float4(kNeg, kNeg, kNeg, kNeg);
    for (int c = tid; c < kN * kN; c += kThreads) {
        const int i = c >> 7, j = c & (kN - 1);
        if (i < j) {
            const float4 q = Q4[sw(colBaseD(j) + i)];
            gS4[c] = make_float4(q.x, q.z, q.w, q.y);  // {s00, s01, s10, s11}
            const uint32_t p = wsBT[rowBase(i) + (j - i - 1)];
            gB4[c] = make_float4((float)(p & 255u), (float)((p >> 8) & 255u),
                                 (float)((p >> 16) & 255u), (float)(p >> 24));
        } else if (i == j) {
            gS4[c] = zeroq;
            gB4[c] = zeroq;
        } else {
            gS4[c] = negq;
            gB4[c] = zeroq;
        }
    }
}

extern "C" void kernel_launch(void* const* d_in, const int* in_sizes, int n_in,
                              void* d_out, int out_size, void* d_ws, size_t ws_size,
                              hipStream_t stream) {
    (void)n_in; (void)out_size; (void)ws_size;
    const float* vinfo = (const float*)d_in[0];  // fp32 [B][N][N]
    const int B = in_sizes[1];                   // b_buffer_size has B elements
    float* outS = (float*)d_out;
    float* outBT = outS + (size_t)B * kN * kN * 4;
    uint32_t* btPacked = (uint32_t*)d_ws;        // needs B*kTri*4 = ~2.1 MB

    hipFuncSetAttribute(reinterpret_cast<const void*>(eisner_dp),
                        hipFuncAttributeMaxDynamicSharedMemorySize, kDynLds);

    eisner_dp<<<dim3(B), dim3(kThreads), kDynLds, stream>>>(vinfo, outS, outBT, btPacked);
}

// Round 14
// 323.191 us; speedup vs baseline: 1.1186x; 1.1186x over previous
//
#include <hip/hip_runtime.h>
#include <stdint.h>

static constexpr int kN = 128;
static constexpr int kTri = (kN * (kN - 1)) / 2;   // 8128 (BT scratch indexing)
static constexpr int kTriD = (kN * (kN + 1)) / 2;  // 8256 cells incl. diagonal
static constexpr int kThreads = 1024;
static constexpr int kSerialK = 16;  // k <= this: one row per lane, no reduction
static constexpr float kNeg = -9999.0f;
static constexpr float kThresh = -9000.0f;
static constexpr float kArcBonus = 5.0f;
static constexpr int kDynLds = kTriD * 16;  // 132,096 B (one float4 quad per cell)

__device__ __forceinline__ int rowBase(int i) { return (i * (2 * kN - 1 - i)) / 2; }
__device__ __forceinline__ int colBaseD(int c) { return (c * (c + 1)) / 2; }  // cells (r<=c, c)

// LDS-only workgroup barrier: orders LDS without draining vmcnt (wsBT stores
// and vL/vR prefetch loads stay in flight across steps).
__device__ __forceinline__ void ldsBarrier() {
    asm volatile("s_waitcnt lgkmcnt(0)\n\ts_barrier" ::: "memory");
}

template <int CTRL>
__device__ __forceinline__ float dppMax(float x) {
    const int y = __builtin_amdgcn_update_dpp(__float_as_int(x), __float_as_int(x),
                                              CTRL, 0xF, 0xF, true);
    return fmaxf(x, __int_as_float(y));
}
__device__ __forceinline__ float swzMax16(float x) {  // xor-16 within 32 lanes
    const int y = __builtin_amdgcn_ds_swizzle(__float_as_int(x), 0x401F);
    return fmaxf(x, __int_as_float(y));
}

// Thread's (i, j, active, P, lp) for step k. Uniform scalar math.
__device__ __forceinline__ void mapK(int k, int tid, int& i, int& j, bool& act,
                                     int& P, int& lp) {
    const int R = kN - k;
    if (k <= kSerialK) {
        P = 1; lp = 0; i = tid; j = tid + k; act = (tid < R);
    } else {
        P = 2; lp = 1;
        while (P < 64 && ((P << 1) * R) <= kThreads) { P <<= 1; ++lp; }
        i = tid >> lp; j = i + k; act = (i < R);
    }
}

// Quad per cell: {x=s00, y=s11, z=s01, w=s10}, col-major incl. diagonal (diag=0).
// SHARED-BASE argmax: p00=(base+vL)+5 and p10=(base+vR)+5 are monotone images
// of the same base sequence => track `base` once (values exact).
// Unroll 8: 16 ds_read_b128 in flight ahead of the cmp/cndmask chains.
__device__ __forceinline__ void scanChunk(const float4* __restrict__ Q4,
                                          int i, int j, int k, int mlo, int mhi,
                                          float vL,
                                          float& bmax, int& ib,
                                          float& v01, int& i01,
                                          float& v11, int& i11) {
    const int qjb = colBaseD(j);  // + r => cell (r, j)
    int q, mstart;
    float4 cur;
    if (mlo == 0) {
        q = i + 1;
        cur = Q4[qjb + q];  // quad(i+1, j); diagonal zeros when k==1
        bmax = cur.z; ib = 0;   // base(0) = 0 + s01[i+1][j]
        const float p00 = (cur.z + vL) + kArcBonus;
        v01 = (p00 > kThresh) ? p00 : kNeg; i01 = 0;  // part00 seed
        mstart = 1;
    } else {
        q = i + mlo;
        cur = Q4[qjb + q];
        mstart = mlo;
    }
    int dA = colBaseD(q) + i;  // cell (i, q)
    int dInc = q + 1;          // colBaseD(q+1) - colBaseD(q)
#pragma unroll 8
    for (int m = mstart; m < mhi; ++m) {
        const float4 nxt = Q4[qjb + q + 1];  // quad(q+1, j); diag zeros at m==k-1
        const float4 diq = Q4[dA];           // quad(i, q)
        const float base = diq.y + nxt.z;    // s11[i][q] + s01[q+1][j]
        // paired adds (v_pk_add_f32-friendly): {p01, p11} = {diq.z,diq.w}+{cur.x,cur.y}
        const float p01 = diq.z + cur.x;     // s01[i][q] + s00[q][j]
        const float p11 = diq.w + cur.y;     // s10[i][q] + s11[q][j]
        if (base > bmax) { bmax = base; ib = m; }  // strict > keeps earliest m
        if (p01 > v01) { v01 = p01; i01 = m; }
        if (p11 > v11) { v11 = p11; i11 = m; }
        cur = nxt;
        dA += dInc; ++dInc;
        ++q;
    }
}

__device__ __forceinline__ void writeCell(float4* __restrict__ Q4,
                                          uint32_t* __restrict__ wsBT,
                                          int i, int j, int k,
                                          float gb, int ib, float vLc, float vRc,
                                          float v01, int i01, float v11, int i11) {
    const float v00 = (gb + vLc) + kArcBonus;
    const float v10 = (gb + vRc) + kArcBonus;
    const float new10 = (v10 > kThresh) ? v10 : kNeg;
    if (new10 > v11) { v11 = new10; i11 = k; }  // q=j candidate; strict > keeps earlier q
    float4 w = make_float4(kNeg, kNeg, kNeg, kNeg);
    uint32_t p = 0;
    if (v00 > kThresh) { w.x = v00; p |= (uint32_t)(i + ib); }
    if (v01 > kThresh) { w.z = v01; p |= (uint32_t)(i + i01) << 8; }
    if (v10 > kThresh) { w.w = v10; p |= (uint32_t)(i + ib) << 16; }
    if (v11 > kThresh) { w.y = v11; p |= (uint32_t)(i + i11) << 24; }
    Q4[colBaseD(j) + i] = w;          // one ds_write_b128
    wsBT[rowBase(i) + k - 1] = p;     // lone global store; not drained per step
}

__global__ __launch_bounds__(kThreads) void eisner_dp(
    const float* __restrict__ vinfo,  // [B][N][N] fp32
    float* __restrict__ outS,         // [B][N][N][2][2] fp32 scores
    float* __restrict__ outBT,        // [B][N][N][2][2] fp32 backtrace (integer-valued)
    uint32_t* __restrict__ btPacked)  // [B][kTri] packed backtrace bytes (d_ws)
{
    extern __shared__ float4 Q4[];

    const int tid = threadIdx.x;
    const int b = blockIdx.x;
    const float* v = vinfo + (size_t)b * kN * kN;
    uint32_t* wsBT = btPacked + (size_t)b * kTri;

    // Diagonal quads = 0. Off-diagonal cells need no init (written before read).
    const float4 zeroq = make_float4(0.f, 0.f, 0.f, 0.f);
    if (tid < kN) Q4[colBaseD(tid) + tid] = zeroq;

    // Prefetch step-1 mapping + vL/vR.
    int ci, cj; bool cact; int cP, clp;
    mapK(1, tid, ci, cj, cact, cP, clp);
    float vL = cact ? v[cj * kN + ci] : 0.f;
    float vR = cact ? v[ci * kN + cj] : 0.f;
    __syncthreads();

    for (int k = 1; k < kN; ++k) {
        const int R = kN - k;
        const int laneId = tid & 63;

        float bmax = -3.0e38f, v01 = -3.0e38f, v11 = -3.0e38f;
        int ib = 0, i01 = 0, i11 = 0x7FFFFFFF;
        const int i = ci, j = cj;
        const bool act = cact;
        const int P = cP, lp = clp;
        const float vLc = vL, vRc = vR;  // prefetch below overwrites vL/vR

        if (P == 1) {
            if (act) {
                scanChunk(Q4, i, j, k, 0, k, vLc, bmax, ib, v01, i01, v11, i11);
            }
        } else {
            int C = ((k + P - 1) >> lp) | 1;  // odd chunk
            const int l = tid & (P - 1);
            const int mlo = l * C;
            const int mhi = (mlo + C < k) ? (mlo + C) : k;
            ib = i01 = 0x7FFFFFFF;
            if (act && mlo < mhi) {
                scanChunk(Q4, i, j, k, mlo, mhi, vLc, bmax, ib, v01, i01, v11, i11);
            }
        }

        // Prefetch next step's mapping + vL/vR (overlaps reduction + barrier).
        if (k + 1 < kN) {
            mapK(k + 1, tid, ci, cj, cact, cP, clp);
            vL = cact ? v[cj * kN + ci] : 0.f;
            vR = cact ? v[ci * kN + cj] : 0.f;
        }

        if (P == 1) {
            if (act) {
                writeCell(Q4, wsBT, i, j, k, bmax, ib, vLc, vRc, v01, i01, v11, i11);
            }
        } else {
            const bool waveActive = (((tid & ~63) >> lp) < R);  // wave-uniform
            if (waveActive) {
                const int l = tid & (P - 1);
                float gB = dppMax<0x4E>(dppMax<0xB1>(bmax));
                float g01 = dppMax<0x4E>(dppMax<0xB1>(v01));
                float g11 = dppMax<0x4E>(dppMax<0xB1>(v11));
                if (P >= 8) {
                    gB = dppMax<0x141>(gB); g01 = dppMax<0x141>(g01); g11 = dppMax<0x141>(g11);
                }
                if (P >= 16) {
                    gB = dppMax<0x140>(gB); g01 = dppMax<0x140>(g01); g11 = dppMax<0x140>(g11);
                }
                if (P >= 32) {
                    gB = swzMax16(gB); g01 = swzMax16(g01); g11 = swzMax16(g11);
                }
                if (P == 64) {
                    gB = fmaxf(gB, __shfl_xor(gB, 32, 64));
                    g01 = fmaxf(g01, __shfl_xor(g01, 32, 64));
                    g11 = fmaxf(g11, __shfl_xor(g11, 32, 64));
                }
                // earliest-m via ballot (contiguous chunks => lane order == m order;
                // empty lanes hold -3e38, can never equal group max)
                const int grpStart = laneId & ~(P - 1);
                const uint64_t gmask =
                    (P == 64) ? ~0ull : (((1ull << P) - 1ull) << grpStart);
                const uint64_t mB = __ballot(bmax == gB) & gmask;
                const uint64_t m2 = __ballot(v01 == g01) & gmask;
                const uint64_t m3 = __ballot(v11 == g11) & gmask;
                const int rB = __shfl(ib, __ffsll((unsigned long long)mB) - 1, 64);
                const int r01 = __shfl(i01, __ffsll((unsigned long long)m2) - 1, 64);
                const int r11 = __shfl(i11, __ffsll((unsigned long long)m3) - 1, 64);
                if (act && l == 0) {
                    writeCell(Q4, wsBT, i, j, k, gB, rB, vLc, vRc, g01, r01, g11, r11);
                }
            }
        }
        ldsBarrier();
    }

    // Full barrier (drains vmcnt) before reading wsBT back.
    __syncthreads();

    // ---- epilogue: emit full [N][N][2][2] scores + backtrace, coalesced ----
    float4* gS4 = (float4*)(outS + (size_t)b * kN * kN * 4);
    float4* gB4 = (float4*)(outBT + (size_t)b * kN * kN * 4);
    const float4 negq = make_float4(kNeg, kNeg, kNeg, kNeg);
    for (int c = tid; c < kN * kN; c += kThreads) {
        const int i = c >> 7, j = c & (kN - 1);
        if (i < j) {
            const float4 q = Q4[colBaseD(j) + i];
            gS4[c] = make_float4(q.x, q.z, q.w, q.y);  // {s00, s01, s10, s11}
            const uint32_t p = wsBT[rowBase(i) + (j - i - 1)];
            gB4[c] = make_float4((float)(p & 255u), (float)((p >> 8) & 255u),
                                 (float)((p >> 16) & 255u), (float)(p >> 24));
        } else if (i == j) {
            gS4[c] = zeroq;
            gB4[c] = zeroq;
        } else {
            gS4[c] = negq;
            gB4[c] = zeroq;
        }
    }
}

extern "C" void kernel_launch(void* const* d_in, const int* in_sizes, int n_in,
                              void* d_out, int out_size, void* d_ws, size_t ws_size,
                              hipStream_t stream) {
    (void)n_in; (void)out_size; (void)ws_size;
    const float* vinfo = (const float*)d_in[0];  // fp32 [B][N][N]
    const int B = in_sizes[1];                   // b_buffer_size has B elements
    float* outS = (float*)d_out;
    float* outBT = outS + (size_t)B * kN * kN * 4;
    uint32_t* btPacked = (uint32_t*)d_ws;        // needs B*kTri*4 = ~2.1 MB

    hipFuncSetAttribute(reinterpret_cast<const void*>(eisner_dp),
                        hipFuncAttributeMaxDynamicSharedMemorySize, kDynLds);

    eisner_dp<<<dim3(B), dim3(kThreads), kDynLds, stream>>>(vinfo, outS, outBT, btPacked);
}

// Round 15
// 297.110 us; speedup vs baseline: 1.2167x; 1.0878x over previous
//
#include <hip/hip_runtime.h>
#include <stdint.h>

static constexpr int kN = 128;
static constexpr int kTri = (kN * (kN - 1)) / 2;   // 8128 (BT scratch indexing)
static constexpr int kTriD = (kN * (kN + 1)) / 2;  // 8256 cells incl. diagonal
static constexpr int kThreads = 1024;
static constexpr float kNeg = -9999.0f;
static constexpr float kThresh = -9000.0f;
static constexpr float kArcBonus = 5.0f;
static constexpr int kDynLds = kTriD * 16;  // 132,096 B (one float4 quad per cell)

__device__ __forceinline__ int rowBase(int i) { return (i * (2 * kN - 1 - i)) / 2; }
__device__ __forceinline__ int colBaseD(int c) { return (c * (c + 1)) / 2; }  // cells (r<=c, c)

// LDS-only workgroup barrier: orders LDS without draining vmcnt (wsBT stores
// and vL/vR prefetch loads stay in flight across steps).
__device__ __forceinline__ void ldsBarrier() {
    asm volatile("s_waitcnt lgkmcnt(0)\n\ts_barrier" ::: "memory");
}

template <int CTRL>
__device__ __forceinline__ float dppMax(float x) {
    const int y = __builtin_amdgcn_update_dpp(__float_as_int(x), __float_as_int(x),
                                              CTRL, 0xF, 0xF, true);
    return fmaxf(x, __int_as_float(y));
}
__device__ __forceinline__ float swzMax16(float x) {  // xor-16 within 32 lanes
    const int y = __builtin_amdgcn_ds_swizzle(__float_as_int(x), 0x401F);
    return fmaxf(x, __int_as_float(y));
}

// Static phase schedule (kN=128, 1024 threads): serial k<=16; P=8 k in [17,63];
// P=16 [64,95]; P=32 [96,111]; P=64 [112,127]. (Same as the old runtime rule.)
__device__ __forceinline__ int lpOf(int k) {
    if (k <= 16) return 0;
    if (k < 64) return 3;
    if (k < 96) return 4;
    if (k < 112) return 5;
    return 6;
}
__device__ __forceinline__ void mapStatic(int nk, int tid, int& i, int& j, bool& act) {
    const int lp = lpOf(nk);
    i = tid >> lp;
    j = i + nk;
    act = i < (kN - nk);
}

// Quad per cell: {x=s00, y=s11, z=s01, w=s10}, col-major incl. diagonal (diag=0).
// SHARED-BASE argmax: p00=(base+vL)+5 and p10=(base+vR)+5 are monotone images
// of the same base sequence => track `base` once (values exact).
__device__ __forceinline__ void scanChunk(const float4* __restrict__ Q4,
                                          int i, int j, int k, int mlo, int mhi,
                                          float vL,
                                          float& bmax, int& ib,
                                          float& v01, int& i01,
                                          float& v11, int& i11) {
    const int qjb = colBaseD(j);  // + r => cell (r, j)
    int q, mstart;
    float4 cur;
    if (mlo == 0) {
        q = i + 1;
        cur = Q4[qjb + q];  // quad(i+1, j); diagonal zeros when k==1
        bmax = cur.z; ib = 0;   // base(0) = 0 + s01[i+1][j]
        const float p00 = (cur.z + vL) + kArcBonus;
        v01 = (p00 > kThresh) ? p00 : kNeg; i01 = 0;  // part00 seed
        mstart = 1;
    } else {
        q = i + mlo;
        cur = Q4[qjb + q];
        mstart = mlo;
    }
    int dA = colBaseD(q) + i;  // cell (i, q)
    int dInc = q + 1;          // colBaseD(q+1) - colBaseD(q)
#pragma unroll 8
    for (int m = mstart; m < mhi; ++m) {
        const float4 nxt = Q4[qjb + q + 1];  // quad(q+1, j); diag zeros at m==k-1
        const float4 diq = Q4[dA];           // quad(i, q)
        const float base = diq.y + nxt.z;    // s11[i][q] + s01[q+1][j]
        const float p01 = diq.z + cur.x;     // s01[i][q] + s00[q][j]
        const float p11 = diq.w + cur.y;     // s10[i][q] + s11[q][j]
        if (base > bmax) { bmax = base; ib = m; }  // strict > keeps earliest m
        if (p01 > v01) { v01 = p01; i01 = m; }
        if (p11 > v11) { v11 = p11; i11 = m; }
        cur = nxt;
        dA += dInc; ++dInc;
        ++q;
    }
}

__device__ __forceinline__ void writeCell(float4* __restrict__ Q4,
                                          uint32_t* __restrict__ wsBT,
                                          int i, int j, int k,
                                          float gb, int ib, float vLc, float vRc,
                                          float v01, int i01, float v11, int i11) {
    const float v00 = (gb + vLc) + kArcBonus;
    const float v10 = (gb + vRc) + kArcBonus;
    const float new10 = (v10 > kThresh) ? v10 : kNeg;
    if (new10 > v11) { v11 = new10; i11 = k; }  // q=j candidate; strict > keeps earlier q
    float4 w = make_float4(kNeg, kNeg, kNeg, kNeg);
    uint32_t p = 0;
    if (v00 > kThresh) { w.x = v00; p |= (uint32_t)(i + ib); }
    if (v01 > kThresh) { w.z = v01; p |= (uint32_t)(i + i01) << 8; }
    if (v10 > kThresh) { w.w = v10; p |= (uint32_t)(i + ib) << 16; }
    if (v11 > kThresh) { w.y = v11; p |= (uint32_t)(i + i11) << 24; }
    Q4[colBaseD(j) + i] = w;          // one ds_write_b128
    wsBT[rowBase(i) + k - 1] = p;     // lone global store; not drained per step
}

// One DP step, P = 1<<LP known at compile time (LP=0 => serial, no reduction).
template <int LP>
__device__ __forceinline__ void doStep(int k, int tid, int laneId,
                                       float4* __restrict__ Q4,
                                       uint32_t* __restrict__ wsBT,
                                       const float* __restrict__ v,
                                       int& ci, int& cj, bool& cact,
                                       float& vL, float& vR) {
    constexpr int P = 1 << LP;
    const int i = ci, j = cj;
    const bool act = cact;
    const float vLc = vL, vRc = vR;  // prefetch below overwrites vL/vR

    float bmax = -3.0e38f, v01 = -3.0e38f, v11 = -3.0e38f;
    int ib = 0x7FFFFFFF, i01 = 0x7FFFFFFF, i11 = 0x7FFFFFFF;

    if constexpr (LP == 0) {
        ib = 0; i01 = 0;
        if (act) {
            scanChunk(Q4, i, j, k, 0, k, vLc, bmax, ib, v01, i01, v11, i11);
        }
        // Prefetch next step's mapping + vL/vR (overlaps write + barrier).
        if (k + 1 < kN) {
            mapStatic(k + 1, tid, ci, cj, cact);
            vL = cact ? v[cj * kN + ci] : 0.f;
            vR = cact ? v[ci * kN + cj] : 0.f;
        }
        if (act) {
            writeCell(Q4, wsBT, i, j, k, bmax, ib, vLc, vRc, v01, i01, v11, i11);
        }
    } else {
        const int C = ((k + P - 1) >> LP) | 1;  // odd chunk
        const int l = tid & (P - 1);
        const int mlo = l * C;
        const int mhi = (mlo + C < k) ? (mlo + C) : k;
        const bool waveActive = (((tid & ~63) >> LP) < (kN - k));  // wave-uniform

        if (waveActive && act && mlo < mhi) {
            scanChunk(Q4, i, j, k, mlo, mhi, vLc, bmax, ib, v01, i01, v11, i11);
        }

        // Prefetch next step's mapping + vL/vR (overlaps reduction + barrier).
        if (k + 1 < kN) {
            mapStatic(k + 1, tid, ci, cj, cact);
            vL = cact ? v[cj * kN + ci] : 0.f;
            vR = cact ? v[ci * kN + cj] : 0.f;
        }

        if (waveActive) {
            // compile-time butterfly: xor1, xor2, mirror8 [, mirror16][, xor16][, xor32]
            float gB = dppMax<0x141>(dppMax<0x4E>(dppMax<0xB1>(bmax)));
            float g01 = dppMax<0x141>(dppMax<0x4E>(dppMax<0xB1>(v01)));
            float g11 = dppMax<0x141>(dppMax<0x4E>(dppMax<0xB1>(v11)));
            if constexpr (P >= 16) {
                gB = dppMax<0x140>(gB); g01 = dppMax<0x140>(g01); g11 = dppMax<0x140>(g11);
            }
            if constexpr (P >= 32) {
                gB = swzMax16(gB); g01 = swzMax16(g01); g11 = swzMax16(g11);
            }
            if constexpr (P == 64) {
                gB = fmaxf(gB, __shfl_xor(gB, 32, 64));
                g01 = fmaxf(g01, __shfl_xor(g01, 32, 64));
                g11 = fmaxf(g11, __shfl_xor(g11, 32, 64));
            }
            // earliest-m via ballot (contiguous chunks => lane order == m order;
            // empty lanes hold -3e38, can never equal group max)
            const int grpStart = laneId & ~(P - 1);
            const uint64_t gmask =
                (P == 64) ? ~0ull : (((1ull << P) - 1ull) << grpStart);
            const uint64_t mB = __ballot(bmax == gB) & gmask;
            const uint64_t m2 = __ballot(v01 == g01) & gmask;
            const uint64_t m3 = __ballot(v11 == g11) & gmask;
            const int rB = __shfl(ib, __ffsll((unsigned long long)mB) - 1, 64);
            const int r01 = __shfl(i01, __ffsll((unsigned long long)m2) - 1, 64);
            const int r11 = __shfl(i11, __ffsll((unsigned long long)m3) - 1, 64);
            if (act && l == 0) {
                writeCell(Q4, wsBT, i, j, k, gB, rB, vLc, vRc, g01, r01, g11, r11);
            }
        }
    }
}

__global__ __launch_bounds__(kThreads) void eisner_dp(
    const float* __restrict__ vinfo,  // [B][N][N] fp32
    float* __restrict__ outS,         // [B][N][N][2][2] fp32 scores
    float* __restrict__ outBT,        // [B][N][N][2][2] fp32 backtrace (integer-valued)
    uint32_t* __restrict__ btPacked)  // [B][kTri] packed backtrace bytes (d_ws)
{
    extern __shared__ float4 Q4[];

    const int tid = threadIdx.x;
    const int laneId = tid & 63;
    const int b = blockIdx.x;
    const float* v = vinfo + (size_t)b * kN * kN;
    uint32_t* wsBT = btPacked + (size_t)b * kTri;

    // Diagonal quads = 0. Off-diagonal cells need no init (written before read).
    const float4 zeroq = make_float4(0.f, 0.f, 0.f, 0.f);
    if (tid < kN) Q4[colBaseD(tid) + tid] = zeroq;

    // Prefetch step-1 mapping + vL/vR.
    int ci, cj; bool cact;
    mapStatic(1, tid, ci, cj, cact);
    float vL = cact ? v[cj * kN + ci] : 0.f;
    float vR = cact ? v[ci * kN + cj] : 0.f;
    __syncthreads();

    for (int k = 1; k <= 16; ++k) {
        doStep<0>(k, tid, laneId, Q4, wsBT, v, ci, cj, cact, vL, vR);
        ldsBarrier();
    }
    for (int k = 17; k < 64; ++k) {
        doStep<3>(k, tid, laneId, Q4, wsBT, v, ci, cj, cact, vL, vR);
        ldsBarrier();
    }
    for (int k = 64; k < 96; ++k) {
        doStep<4>(k, tid, laneId, Q4, wsBT, v, ci, cj, cact, vL, vR);
        ldsBarrier();
    }
    for (int k = 96; k < 112; ++k) {
        doStep<5>(k, tid, laneId, Q4, wsBT, v, ci, cj, cact, vL, vR);
        ldsBarrier();
    }
    for (int k = 112; k < 128; ++k) {
        doStep<6>(k, tid, laneId, Q4, wsBT, v, ci, cj, cact, vL, vR);
        ldsBarrier();
    }

    // Full barrier (drains vmcnt) before reading wsBT back.
    __syncthreads();

    // ---- epilogue: emit full [N][N][2][2] scores + backtrace, coalesced ----
    float4* gS4 = (float4*)(outS + (size_t)b * kN * kN * 4);
    float4* gB4 = (float4*)(outBT + (size_t)b * kN * kN * 4);
    const float4 negq = make_float4(kNeg, kNeg, kNeg, kNeg);
    for (int c = tid; c < kN * kN; c += kThreads) {
        const int i = c >> 7, j = c & (kN - 1);
        if (i < j) {
            const float4 q = Q4[colBaseD(j) + i];
            gS4[c] = make_float4(q.x, q.z, q.w, q.y);  // {s00, s01, s10, s11}
            const uint32_t p = wsBT[rowBase(i) + (j - i - 1)];
            gB4[c] = make_float4((float)(p & 255u), (float)((p >> 8) & 255u),
                                 (float)((p >> 16) & 255u), (float)(p >> 24));
        } else if (i == j) {
            gS4[c] = zeroq;
            gB4[c] = zeroq;
        } else {
            gS4[c] = negq;
            gB4[c] = zeroq;
        }
    }
}

extern "C" void kernel_launch(void* const* d_in, const int* in_sizes, int n_in,
                              void* d_out, int out_size, void* d_ws, size_t ws_size,
                              hipStream_t stream) {
    (void)n_in; (void)out_size; (void)ws_size;
    const float* vinfo = (const float*)d_in[0];  // fp32 [B][N][N]
    const int B = in_sizes[1];                   // b_buffer_size has B elements
    float* outS = (float*)d_out;
    float* outBT = outS + (size_t)B * kN * kN * 4;
    uint32_t* btPacked = (uint32_t*)d_ws;        // needs B*kTri*4 = ~2.1 MB

    hipFuncSetAttribute(reinterpret_cast<const void*>(eisner_dp),
                        hipFuncAttributeMaxDynamicSharedMemorySize, kDynLds);

    eisner_dp<<<dim3(B), dim3(kThreads), kDynLds, stream>>>(vinfo, outS, outBT, btPacked);
}